// Round 11
// baseline (354.143 us; speedup 1.0000x reference)
//
#include <hip/hip_runtime.h>
#include <hip/hip_bf16.h>
#include <math.h>

#define NTOK 3136           // 16*14*14 tokens
#define MT 12544            // 4 * NTOK
#define KCV 2304            // 3*3*16*16
#define THRESH 1.5f
#define LN_EPS 1e-5f

typedef short short8 __attribute__((ext_vector_type(8)));
typedef float f32x4 __attribute__((ext_vector_type(4)));

// ---------- bf16 helpers ----------
__device__ __forceinline__ unsigned short f2bf(float f) {   // manual RTNE (cold paths)
    unsigned int u = __float_as_uint(f);
    u += 0x7fffu + ((u >> 16) & 1u);
    return (unsigned short)(u >> 16);
}
__device__ __forceinline__ float bf2f(unsigned short h) {
    return __uint_as_float(((unsigned int)h) << 16);
}
// HW packed cvt (v_cvt_pk_bf16_f32, RTNE): low16 = bf(x0), high16 = bf(x1)
__device__ __forceinline__ unsigned int cvt_pk_bf16(float x0, float x1) {
    union { __hip_bfloat162 h; unsigned int u; } cv;
    cv.h = __float22bfloat162_rn(make_float2(x0, x1));
    return cv.u;
}
__device__ __forceinline__ void async16(const void* g, void* l) {
    __builtin_amdgcn_global_load_lds((const __attribute__((address_space(1))) void*)g,
                                     (__attribute__((address_space(3))) void*)l, 16, 0, 0);
}

// ---------- wave helpers (wave = 64) ----------
__device__ __forceinline__ float wsum(float v) {
#pragma unroll
    for (int o = 32; o > 0; o >>= 1) v += __shfl_xor(v, o);
    return v;
}
__device__ __forceinline__ float wmax(float v) {
#pragma unroll
    for (int o = 32; o > 0; o >>= 1) v = fmaxf(v, __shfl_xor(v, o));
    return v;
}

// ---------- prep mega-kernel ----------
// blocks 0..287      : split_cw -> hi/lo bf16, permuted [kg][e][8]
// blocks 288..1567   : cast wk|wv|in_proj -> bf16 pool (offsets 0 / 65536 / 131072)
// block  1568        : query path -> qp[256]
// blocks 1569..1824  : D1 = dense_w @ out_proj_w (fp32, row per block)
// block  1825        : tvec = dense_w @ out_proj_b + dense_b + gq
__global__ __launch_bounds__(256) void prep_k(
    const float* __restrict__ cw, unsigned short* __restrict__ cwh,
    unsigned short* __restrict__ cwl,
    const float* __restrict__ s0, const float* __restrict__ s1, const float* __restrict__ s2,
    unsigned short* __restrict__ dst,
    const float* __restrict__ gq, const float* __restrict__ wq_w,
    const float* __restrict__ wq_b, const float* __restrict__ lnq_g,
    const float* __restrict__ lnq_b, const float* __restrict__ inW,
    const float* __restrict__ inB, float* __restrict__ qp,
    const float* __restrict__ Wd, const float* __restrict__ Wo,
    const float* __restrict__ bo, const float* __restrict__ bd,
    float* __restrict__ D1, float* __restrict__ tvec)
{
    const int blk = blockIdx.x;
    const int t = threadIdx.x;
    if (blk < 288) {
        int i = blk * 256 + t;                   // 288 kg * 256 e
        int e = i & 255, kg = i >> 8;
        const float4* sp = (const float4*)(cw + (size_t)e * KCV + kg * 8);
        float4 x0 = sp[0], x1 = sp[1];
        float av[8] = {x0.x, x0.y, x0.z, x0.w, x1.x, x1.y, x1.z, x1.w};
        short8 hh, ll;
#pragma unroll
        for (int j = 0; j < 8; ++j) {
            unsigned short h = f2bf(av[j]);
            hh[j] = (short)h;
            ll[j] = (short)f2bf(av[j] - bf2f(h));
        }
        size_t off = (size_t)kg * 2048 + e * 8;
        *(short8*)&cwh[off] = hh;
        *(short8*)&cwl[off] = ll;
    } else if (blk < 1568) {
        int i = (blk - 288) * 256 + t;           // 327680 total
        if (i >= 327680) return;
        float v;
        if      (i <  65536) v = s0[i];
        else if (i < 131072) v = s1[i - 65536];
        else                 v = s2[i - 131072];
        dst[i] = f2bf(v);
    } else if (blk == 1568) {
        // query path: qp[256], batch-invariant, fp32
        __shared__ float sh[256];
        __shared__ float red[256];
        float acc = wq_b[t];
        for (int j = 0; j < 256; j++) acc += gq[j] * wq_w[t * 256 + j];
        red[t] = acc; __syncthreads();
        for (int o = 128; o > 0; o >>= 1) { if (t < o) red[t] += red[t + o]; __syncthreads(); }
        float m = red[0] * (1.f / 256.f);
        __syncthreads();
        float d = acc - m;
        red[t] = d * d; __syncthreads();
        for (int o = 128; o > 0; o >>= 1) { if (t < o) red[t] += red[t + o]; __syncthreads(); }
        float inv = 1.f / sqrtf(red[0] * (1.f / 256.f) + LN_EPS);
        sh[t] = d * inv * lnq_g[t] + lnq_b[t];
        __syncthreads();
        float a2 = inB[t];
        for (int j = 0; j < 256; j++) a2 += sh[j] * inW[t * 256 + j];
        qp[t] = a2 * 0.125f;
    } else if (blk < 1825) {
        // D1 row i: D1[i][j] = sum_k Wd[i][k] * Wo[k][j]
        int i = blk - 1569;
        float acc = 0.f;
        for (int k = 0; k < 256; k++) acc += Wd[i * 256 + k] * Wo[k * 256 + t];
        D1[i * 256 + t] = acc;
    } else {
        // tvec[i] = sum_k Wd[i][k]*bo[k] + bd[i] + gq[i]
        float acc = bd[t] + gq[t];
        for (int k = 0; k < 256; k++) acc += Wd[t * 256 + k] * bo[k];
        tvec[t] = acc;
    }
}

// ---------- conv implicit GEMM (v5, proven 82.5us) + prep2 piggyback blocks ----------
// blocks 0..783 : conv. 64m x 64e, XCD swizzle, BK=64. A in registers (frag layout),
//   prefetch depth 1; B reg-staged + ds_write (barrier drains lgkm only).
// blocks 784..1039 : Wc row = bproj_w @ D1 -> bf16.  block 1040 : bc vector.
__global__ __launch_bounds__(256) void conv_mfma_k(
    const float* __restrict__ video, const unsigned short* __restrict__ cwh,
    const unsigned short* __restrict__ cwl, const float* __restrict__ cbias,
    float* __restrict__ tokmean4, unsigned short* __restrict__ outB,
    const float* __restrict__ Wb, const float* __restrict__ D1,
    const float* __restrict__ tvec, const float* __restrict__ bb,
    unsigned short* __restrict__ WcB, float* __restrict__ bc)
{
    __shared__ __align__(16) unsigned short Bh[8192], Bl[8192];  // 2 bufs x [kg8][e64][8]
    const int t    = threadIdx.x;
    if (blockIdx.x >= 784) {
        const int pblk = blockIdx.x - 784;
        if (pblk < 256) {
            float acc = 0.f;
            for (int k = 0; k < 256; k++) acc += Wb[pblk * 256 + k] * D1[k * 256 + t];
            WcB[pblk * 256 + t] = f2bf(acc);
        } else {
            float acc = bb[t];
            for (int k = 0; k < 256; k++) acc += Wb[t * 256 + k] * tvec[k];
            bc[t] = acc;
        }
        return;
    }
    const int lane = t & 63;
    const int w    = t >> 6;
    const int l15  = lane & 15, lq = lane >> 4;
    const int v_  = blockIdx.x;
    const int s_  = (v_ & 7) * 98 + (v_ >> 3);
    const int mb  = s_ >> 2, eb = s_ & 3;
    const int m0  = mb * 64, e0 = eb * 64;

    const int m = m0 + w * 16 + l15;
    const int b = m / NTOK, n = m % NTOK;
    const int d = n / 196, hw = n % 196;
    const int h = hw / 14, ww = hw % 14;
    const float* vb = video + (size_t)(b * 3) * (32 * 50176) + (h * 16) * 224 + ww * 16;
    const int dbase = 2 * d - 1;

    f32x4 acc[4] = {};
    float4 a0, a1, a2, a3, b0, b1, b2, b3;
    short8 rh0, rh1, rl0, rl1;

#define BLOAD(s)                                                                     \
    {                                                                                \
        const size_t g0 = (size_t)((s) * 8 + w) * 2048 + (e0 + lane) * 8;            \
        const size_t g1 = g0 + 4 * 2048;                                             \
        rh0 = *(const short8*)(cwh + g0);                                            \
        rh1 = *(const short8*)(cwh + g1);                                            \
        rl0 = *(const short8*)(cwl + g0);                                            \
        rl1 = *(const short8*)(cwl + g1);                                            \
    }
#define BSTORE(buf)                                                                  \
    {                                                                                \
        const int o = (buf) * 4096 + w * 512 + lane * 8;                             \
        *(short8*)&Bh[o]        = rh0;                                               \
        *(short8*)&Bh[o + 2048] = rh1;                                               \
        *(short8*)&Bl[o]        = rl0;                                               \
        *(short8*)&Bl[o + 2048] = rl1;                                               \
    }
#define LOAD_A32(k0v, x0, x1)                                                        \
    {                                                                                \
        const int k0  = (k0v) + lq * 8;                                              \
        const int c   = k0 / 768;                                                    \
        const int rem = k0 - c * 768;                                                \
        const int kd  = rem >> 8;                                                    \
        const int r2  = rem & 255;                                                   \
        const int id  = dbase + kd;                                                  \
        x0 = make_float4(0.f, 0.f, 0.f, 0.f); x1 = x0;                               \
        if (id >= 0) {                                                               \
            const float* p = vb + (size_t)c * (32 * 50176) + id * 50176 +            \
                             (r2 >> 4) * 224 + (r2 & 15);                            \
            x0 = *(const float4*)p;                                                  \
            x1 = *(const float4*)(p + 4);                                            \
        }                                                                            \
    }
#define CVT_AB(y0, y1, fah, fal)                                                     \
    short8 fah, fal;                                                                 \
    {                                                                                \
        float av[8] = {y0.x, y0.y, y0.z, y0.w, y1.x, y1.y, y1.z, y1.w};              \
        unsigned int ph[4], pl[4];                                                   \
        _Pragma("unroll")                                                            \
        for (int j = 0; j < 4; ++j) {                                                \
            float u0 = av[2 * j], u1 = av[2 * j + 1];                                \
            unsigned int hu = cvt_pk_bf16(u0, u1);                                   \
            float r0 = u0 - __uint_as_float(hu << 16);                               \
            float r1 = u1 - __uint_as_float(hu & 0xffff0000u);                       \
            ph[j] = hu;                                                              \
            pl[j] = cvt_pk_bf16(r0, r1);                                             \
        }                                                                            \
        int4 phv = make_int4(ph[0], ph[1], ph[2], ph[3]);                            \
        int4 plv = make_int4(pl[0], pl[1], pl[2], pl[3]);                            \
        fah = *(short8*)&phv;                                                        \
        fal = *(short8*)&plv;                                                        \
    }

    BLOAD(0);
    LOAD_A32(0, a0, a1);
    LOAD_A32(32, a2, a3);
    BSTORE(0);
    __syncthreads();

    for (int s = 0; s < 36; ++s) {
        const int cbuf = s & 1;
        if (s + 1 < 36) {
            BLOAD(s + 1);
            LOAD_A32((s + 1) * 64,      b0, b1);
            LOAD_A32((s + 1) * 64 + 32, b2, b3);
        }
        {
            CVT_AB(a0, a1, fah, fal);
            const int rb = cbuf * 4096 + lq * 512 + l15 * 8;
#pragma unroll
            for (int ct = 0; ct < 4; ++ct) {
                short8 fbh = *(const short8*)&Bh[rb + ct * 128];
                short8 fbl = *(const short8*)&Bl[rb + ct * 128];
                acc[ct] = __builtin_amdgcn_mfma_f32_16x16x32_bf16(fah, fbh, acc[ct], 0, 0, 0);
                acc[ct] = __builtin_amdgcn_mfma_f32_16x16x32_bf16(fah, fbl, acc[ct], 0, 0, 0);
                acc[ct] = __builtin_amdgcn_mfma_f32_16x16x32_bf16(fal, fbh, acc[ct], 0, 0, 0);
            }
        }
        {
            CVT_AB(a2, a3, fah, fal);
            const int rb = cbuf * 4096 + (4 + lq) * 512 + l15 * 8;
#pragma unroll
            for (int ct = 0; ct < 4; ++ct) {
                short8 fbh = *(const short8*)&Bh[rb + ct * 128];
                short8 fbl = *(const short8*)&Bl[rb + ct * 128];
                acc[ct] = __builtin_amdgcn_mfma_f32_16x16x32_bf16(fah, fbh, acc[ct], 0, 0, 0);
                acc[ct] = __builtin_amdgcn_mfma_f32_16x16x32_bf16(fah, fbl, acc[ct], 0, 0, 0);
                acc[ct] = __builtin_amdgcn_mfma_f32_16x16x32_bf16(fal, fbh, acc[ct], 0, 0, 0);
            }
        }
        if (s + 1 < 36) BSTORE(cbuf ^ 1);
        __syncthreads();
        a0 = b0; a1 = b1; a2 = b2; a3 = b3;
    }
#undef BLOAD
#undef BSTORE
#undef LOAD_A32
#undef CVT_AB

    // C/D: col(e) = lane&15, row(m) = (lane>>4)*4 + reg  [m89]
    const int rbase = m0 + w * 16 + lq * 4;
    float rsum[4] = {0.f, 0.f, 0.f, 0.f};
#pragma unroll
    for (int ct = 0; ct < 4; ++ct) {
        int e = e0 + ct * 16 + l15;
        float bias = cbias[e];
#pragma unroll
        for (int r = 0; r < 4; ++r) {
            float vv = fmaxf(acc[ct][r] + bias, 0.f);
            outB[(size_t)(rbase + r) * 256 + e] = f2bf(vv);
            rsum[r] += vv;
        }
    }
    if (m0 < NTOK) {
#pragma unroll
        for (int r = 0; r < 4; ++r) {
            float sv = rsum[r];
            sv += __shfl_xor(sv, 1); sv += __shfl_xor(sv, 2);
            sv += __shfl_xor(sv, 4); sv += __shfl_xor(sv, 8);
            if (l15 == 0) tokmean4[(size_t)eb * NTOK + rbase + r] = sv;
        }
    }
}

// ---------- fused dual GEMM (blocks 0..1567) + boundary piggyback (1568..2351) ----------
__global__ __launch_bounds__(256) void gemm_dual_k(
    const unsigned short* __restrict__ A0, const unsigned short* __restrict__ A1,
    const unsigned short* __restrict__ W,
    const float* __restrict__ bias0, const float* __restrict__ bias1,
    unsigned short* __restrict__ outB0, unsigned short* __restrict__ outB1,
    const float* __restrict__ tokmean4, const float* __restrict__ ent_table,
    int* __restrict__ boundary)
{
    __shared__ __align__(16) unsigned short As[8192], Bs[8192];
    const int t = threadIdx.x, lane = t & 63, w = t >> 6;
    if (blockIdx.x >= 1568) {
        // boundary: one wave per token (needs tokmean4 from conv launch)
        int n = (blockIdx.x - 1568) * 4 + w;
        float s0 = tokmean4[n];
        float s1 = tokmean4[NTOK + n];
        float s2 = tokmean4[2 * NTOK + n];
        float s3 = tokmean4[3 * NTOK + n];
        float mean = ((s0 + s1) + (s2 + s3)) * (1.f / 256.f);   // deterministic order
        float bf = rintf(mean * 255.f);
        bf = fminf(fmaxf(bf, 0.f), 255.f);
        int byte = (int)bf;
        const float4 lg = reinterpret_cast<const float4*>(ent_table + byte * 256)[lane];
        float mx = wmax(fmaxf(fmaxf(lg.x, lg.y), fmaxf(lg.z, lg.w)));
        float e0 = expf(lg.x - mx), e1 = expf(lg.y - mx);
        float e2 = expf(lg.z - mx), e3 = expf(lg.w - mx);
        float z = wsum(e0 + e1 + e2 + e3);
        float iz = 1.f / z;
        float p0 = e0 * iz, p1 = e1 * iz, p2 = e2 * iz, p3 = e3 * iz;
        float ep = -(p0 * log2f(p0 + 1e-9f) + p1 * log2f(p1 + 1e-9f) +
                     p2 * log2f(p2 + 1e-9f) + p3 * log2f(p3 + 1e-9f));
        ep = wsum(ep);
        if (lane == 0) boundary[n] = (ep > THRESH) ? 1 : 0;
        return;
    }
    const int v_ = blockIdx.x;
    const int s_ = (v_ & 7) * 196 + (v_ >> 3);         // 1568 = 8*196
    const int mb = s_ >> 3, ebg = s_ & 7;              // ebg 0..7 over 512 W rows
    const int half = ebg >> 2;
    const unsigned short* A = half ? A1 : A0;
    const float* bias = half ? bias1 : bias0;
    unsigned short* outB = half ? outB1 : outB0;
    const int m0 = mb * 64, eg0 = ebg * 64, el0 = (ebg & 3) * 64;
    const int l15 = lane & 15, lq = lane >> 4;
    const unsigned short* ga = A + (size_t)(m0 + lane) * 256;
    const unsigned short* gb = W + (size_t)(eg0 + lane) * 256;
#pragma unroll
    for (int kg = w; kg < 16; kg += 4) {
        async16(ga + kg * 8, &As[kg * 512]);
        async16(gb + kg * 8, &Bs[kg * 512]);
    }
    f32x4 acc[4] = {};
    __syncthreads();
#pragma unroll
    for (int s = 0; s < 4; ++s) {
        int kg = s * 4 + lq;
        short8 a = *(const short8*)&As[kg * 512 + (w * 16 + l15) * 8];
#pragma unroll
        for (int ct = 0; ct < 4; ++ct) {
            short8 bb = *(const short8*)&Bs[kg * 512 + (ct * 16 + l15) * 8];
            acc[ct] = __builtin_amdgcn_mfma_f32_16x16x32_bf16(a, bb, acc[ct], 0, 0, 0);
        }
    }
    __syncthreads();
#pragma unroll
    for (int kg = w; kg < 16; kg += 4) {
        async16(ga + (16 + kg) * 8, &As[kg * 512]);
        async16(gb + (16 + kg) * 8, &Bs[kg * 512]);
    }
    __syncthreads();
#pragma unroll
    for (int s = 0; s < 4; ++s) {
        int kg = s * 4 + lq;
        short8 a = *(const short8*)&As[kg * 512 + (w * 16 + l15) * 8];
#pragma unroll
        for (int ct = 0; ct < 4; ++ct) {
            short8 bb = *(const short8*)&Bs[kg * 512 + (ct * 16 + l15) * 8];
            acc[ct] = __builtin_amdgcn_mfma_f32_16x16x32_bf16(a, bb, acc[ct], 0, 0, 0);
        }
    }
    int rbase = m0 + w * 16 + lq * 4;
#pragma unroll
    for (int ct = 0; ct < 4; ++ct) {
        int e = el0 + ct * 16 + l15;
        float bv = bias[e];
#pragma unroll
        for (int r = 0; r < 4; ++r) {
            float vv = acc[ct][r] + bv;
            outB[(size_t)(rbase + r) * 256 + e] = f2bf(vv);
        }
    }
}

// ---------- LN-fused dual GEMM (blocks 0..1567) + scan piggyback (block 1568) ----------
// B staged in TWO phases (16KB). half0 (kp): scores epilogue (dot qp), kp never
// stored. half1 (vp): store bf16.
__global__ __launch_bounds__(256, 2) void gemm_ln_k(
    const unsigned short* __restrict__ A0, const unsigned short* __restrict__ A1,
    const unsigned short* __restrict__ W,
    const float* __restrict__ bias0, const float* __restrict__ bias1,
    const float* __restrict__ g0, const float* __restrict__ b0,
    const float* __restrict__ g1, const float* __restrict__ b1,
    unsigned short* __restrict__ outVp, const float* __restrict__ qp,
    float* __restrict__ sc,
    const int* __restrict__ boundary, int* __restrict__ seg_start, int* __restrict__ Sptr)
{
    __shared__ __align__(16) unsigned short As[16384], Bs[8192];   // 32 KB + 16 KB
    __shared__ float pst[2][4][64];
    __shared__ float rmean[64], rinv[64];
    __shared__ int sums[256];
    const int t = threadIdx.x, lane = t & 63, w = t >> 6;
    if (blockIdx.x >= 1568) {
        // single-block scan: boundary -> seg_start[], S
        const int CH = 13;
        int base = t * CH;
        int s = 0;
        for (int i = 0; i < CH; i++) { int n = base + i; if (n < NTOK) s += boundary[n]; }
        sums[t] = s; __syncthreads();
        for (int o = 1; o < 256; o <<= 1) {
            int v = sums[t];
            int u = (t >= o) ? sums[t - o] : 0;
            __syncthreads();
            sums[t] = v + u;
            __syncthreads();
        }
        int run = (t == 0) ? 0 : sums[t - 1];
        if (t == 0) seg_start[0] = 0;
        for (int i = 0; i < CH; i++) {
            int n = base + i;
            if (n >= NTOK) break;
            int v = boundary[n];
            if (n == NTOK - 1) { Sptr[0] = run + 1; seg_start[run + 1] = NTOK; }
            if (v && (n + 1 < NTOK)) seg_start[run + 1] = n + 1;
            run += v;
        }
        return;
    }
    const int v_ = blockIdx.x;
    const int s_ = (v_ & 7) * 196 + (v_ >> 3);         // 1568 = 8*196
    const int mb = s_ >> 3, ebg = s_ & 7;
    const int half = ebg >> 2;
    const unsigned short* A = half ? A1 : A0;
    const float* bias = half ? bias1 : bias0;
    const float* lng  = half ? g1 : g0;
    const float* lnb  = half ? b1 : b0;
    const int m0 = mb * 64, eg0 = ebg * 64, el0 = (ebg & 3) * 64;
    const int l15 = lane & 15, lq = lane >> 4;
    const unsigned short* ga = A + (size_t)(m0 + lane) * 256;
    const unsigned short* gb = W + (size_t)(eg0 + lane) * 256;
    // stage FULL A (32 kg) + B phase 1 (kg 0..15)
#pragma unroll
    for (int kg = w; kg < 32; kg += 4) async16(ga + kg * 8, &As[kg * 512]);
#pragma unroll
    for (int kg = w; kg < 16; kg += 4) async16(gb + kg * 8, &Bs[kg * 512]);
    __syncthreads();
    // row stats: lane l owns row l; wave w sums its kg quarter [w*8, w*8+8)
    {
        float sum = 0.f, sq = 0.f;
#pragma unroll
        for (int k8 = 0; k8 < 8; ++k8) {
            short8 x = *(const short8*)&As[(w * 8 + k8) * 512 + lane * 8];
#pragma unroll
            for (int j = 0; j < 8; ++j) {
                float xv = bf2f((unsigned short)x[j]);
                sum += xv; sq += xv * xv;
            }
        }
        pst[0][w][lane] = sum; pst[1][w][lane] = sq;
    }
    __syncthreads();
    if (w == 0) {
        float s4 = (pst[0][0][lane] + pst[0][1][lane]) + (pst[0][2][lane] + pst[0][3][lane]);
        float q4 = (pst[1][0][lane] + pst[1][1][lane]) + (pst[1][2][lane] + pst[1][3][lane]);
        float mean = s4 * (1.f / 256.f);
        float var  = q4 * (1.f / 256.f) - mean * mean;
        rmean[lane] = mean;
        rinv[lane]  = 1.f / sqrtf(var + LN_EPS);
    }
    __syncthreads();
    const float myMean = rmean[w * 16 + l15];
    const float myInv  = rinv [w * 16 + l15];

    f32x4 acc[4] = {};
#pragma unroll
    for (int ph = 0; ph < 2; ++ph) {
        if (ph == 1) {
            __syncthreads();                       // phase-1 B reads done
#pragma unroll
            for (int kg = w; kg < 16; kg += 4) async16(gb + (16 + kg) * 8, &Bs[kg * 512]);
            __syncthreads();
        }
#pragma unroll
        for (int s = 0; s < 4; ++s) {
            int kg = ph * 16 + s * 4 + lq;         // global kg 0..31
            short8 araw = *(const short8*)&As[kg * 512 + (w * 16 + l15) * 8];
            float4 gA = *(const float4*)&lng[kg * 8];
            float4 gB = *(const float4*)&lng[kg * 8 + 4];
            float4 bA = *(const float4*)&lnb[kg * 8];
            float4 bB = *(const float4*)&lnb[kg * 8 + 4];
            float y[8];
            y[0] = (bf2f((unsigned short)araw[0]) - myMean) * myInv * gA.x + bA.x;
            y[1] = (bf2f((unsigned short)araw[1]) - myMean) * myInv * gA.y + bA.y;
            y[2] = (bf2f((unsigned short)araw[2]) - myMean) * myInv * gA.z + bA.z;
            y[3] = (bf2f((unsigned short)araw[3]) - myMean) * myInv * gA.w + bA.w;
            y[4] = (bf2f((unsigned short)araw[4]) - myMean) * myInv * gB.x + bB.x;
            y[5] = (bf2f((unsigned short)araw[5]) - myMean) * myInv * gB.y + bB.y;
            y[6] = (bf2f((unsigned short)araw[6]) - myMean) * myInv * gB.z + bB.z;
            y[7] = (bf2f((unsigned short)araw[7]) - myMean) * myInv * gB.w + bB.w;
            int4 pk = make_int4(cvt_pk_bf16(y[0], y[1]), cvt_pk_bf16(y[2], y[3]),
                                cvt_pk_bf16(y[4], y[5]), cvt_pk_bf16(y[6], y[7]));
            short8 a = *(short8*)&pk;
            const int bkg = s * 4 + lq;            // B buffer index (0..15)
#pragma unroll
            for (int ct = 0; ct < 4; ++ct) {
                short8 bb = *(const short8*)&Bs[bkg * 512 + (ct * 16 + l15) * 8];
                acc[ct] = __builtin_amdgcn_mfma_f32_16x16x32_bf16(a, bb, acc[ct], 0, 0, 0);
            }
        }
    }
    int rbase = m0 + w * 16 + lq * 4;
    if (half == 0) {
        float sp[4] = {0.f, 0.f, 0.f, 0.f};
#pragma unroll
        for (int ct = 0; ct < 4; ++ct) {
            int e = el0 + ct * 16 + l15;
            float bv = bias[e];
            float qv = qp[e];
#pragma unroll
            for (int r = 0; r < 4; ++r) sp[r] += (acc[ct][r] + bv) * qv;
        }
#pragma unroll
        for (int r = 0; r < 4; ++r) {
            sp[r] += __shfl_xor(sp[r], 1); sp[r] += __shfl_xor(sp[r], 2);
            sp[r] += __shfl_xor(sp[r], 4); sp[r] += __shfl_xor(sp[r], 8);
        }
        if (l15 == 0) {
#pragma unroll
            for (int r = 0; r < 4; ++r) {
                int mm = rbase + r;
                int bb = mm / NTOK, nn = mm % NTOK;
                sc[(bb * 4 + ebg) * NTOK + nn] = sp[r];
            }
        }
    } else {
#pragma unroll
        for (int ct = 0; ct < 4; ++ct) {
            int e = el0 + ct * 16 + l15;
            float bv = bias[e];
#pragma unroll
            for (int r = 0; r < 4; ++r) {
                float vv = acc[ct][r] + bv;
                outVp[(size_t)(rbase + r) * 256 + e] = f2bf(vv);
            }
        }
    }
}

// ---------- fused attention + final projection ----------
// Grid (49, 4): block = 64-segment band x batch. Phase A: wave h = head h serially
// does softmax-PV for the band's segments, writing bf16 attn rows DIRECTLY into the
// MFMA A-fragment LDS layout (masked rows -> 0). Phase B: 64x256 GEMM vs Wc (streamed
// in 4 e-chunks x 2 k-phases), + bc, S-mask, fp32 out. Replaces attn_bf_k +
// gemm_single_k: same bf16 rounding points -> bit-identical numerics, minus a launch
// and a 12.8 MB global round-trip.
__global__ __launch_bounds__(256) void attn_proj_k(
    const float* __restrict__ sc, const unsigned short* __restrict__ vp,
    const int* __restrict__ seg_start, const int* __restrict__ Sptr,
    const unsigned short* __restrict__ WcB, const float* __restrict__ bc,
    float* __restrict__ out)
{
    __shared__ __align__(16) unsigned short As[16384], Bs[8192];   // 32 KB + 16 KB
    const int t = threadIdx.x, lane = t & 63, w = t >> 6;
    const int m0 = blockIdx.x * 64;          // segment band
    const int b  = blockIdx.y;
    const int l15 = lane & 15, lq = lane >> 4;
    const int S = *Sptr;

    // ---- Phase A: wave w = head w; softmax rows -> As in frag layout ----
    {
        const int h = w;
        const float* scr = sc + (b * 4 + h) * NTOK;
        const unsigned short* vpb0 = vp + (size_t)b * NTOK * 256 + h * 64 + lane;
        const int adst = ((h * 8 + (lane >> 3)) * 64) * 8 + (lane & 7);
        for (int mseg = 0; mseg < 64; ++mseg) {
            int s = m0 + mseg;
            unsigned short val = 0;
            if (s < S) {
                int st = seg_start[s], en = seg_start[s + 1];
                float mx = -1e30f;
                for (int n = st; n < en; n++) mx = fmaxf(mx, scr[n]);
                float den = 0.f, acc = 0.f;
                for (int n = st; n < en; n++) {
                    float wgt = expf(scr[n] - mx);
                    den += wgt;
                    acc += wgt * bf2f(vpb0[(size_t)n * 256]);
                }
                val = f2bf(acc / den);
            }
            As[adst + mseg * 8] = val;
        }
    }
    __syncthreads();

    // ---- Phase B: out[band] = AsRows @ Wc^T + bc (4 e-chunks x 2 k-phases) ----
    const int rb_m = w * 16 + lq * 4;        // m (segment-in-band) base for this lane
#pragma unroll 1
    for (int ec = 0; ec < 4; ++ec) {
        const unsigned short* gb = WcB + (size_t)(ec * 64 + lane) * 256;
        f32x4 acc[4] = {};
        // k-phase 1: kg 0..15
#pragma unroll
        for (int kg = w; kg < 16; kg += 4) async16(gb + kg * 8, &Bs[kg * 512]);
        __syncthreads();
#pragma unroll
        for (int s4 = 0; s4 < 4; ++s4) {
            int kg = s4 * 4 + lq;
            short8 a = *(const short8*)&As[kg * 512 + (w * 16 + l15) * 8];
#pragma unroll
            for (int ct = 0; ct < 4; ++ct) {
                short8 bb = *(const short8*)&Bs[kg * 512 + (ct * 16 + l15) * 8];
                acc[ct] = __builtin_amdgcn_mfma_f32_16x16x32_bf16(a, bb, acc[ct], 0, 0, 0);
            }
        }
        __syncthreads();
        // k-phase 2: kg 16..31
#pragma unroll
        for (int kg = w; kg < 16; kg += 4) async16(gb + (16 + kg) * 8, &Bs[kg * 512]);
        __syncthreads();
#pragma unroll
        for (int s4 = 0; s4 < 4; ++s4) {
            int kgg = 16 + s4 * 4 + lq;
            short8 a = *(const short8*)&As[kgg * 512 + (w * 16 + l15) * 8];
#pragma unroll
            for (int ct = 0; ct < 4; ++ct) {
                short8 bb = *(const short8*)&Bs[(s4 * 4 + lq) * 512 + (ct * 16 + l15) * 8];
                acc[ct] = __builtin_amdgcn_mfma_f32_16x16x32_bf16(a, bb, acc[ct], 0, 0, 0);
            }
        }
        __syncthreads();                     // Bs free for next ec
        // epilogue for this e-chunk
#pragma unroll
        for (int ct = 0; ct < 4; ++ct) {
            int e = ec * 64 + ct * 16 + l15;
            float bv = bc[e];
#pragma unroll
            for (int r = 0; r < 4; ++r) {
                int s = m0 + rb_m + r;
                float vv = acc[ct][r] + bv;
                if (s >= S) vv = 0.f;
                out[((size_t)b * NTOK + s) * 256 + e] = vv;
            }
        }
    }
}

extern "C" void kernel_launch(void* const* d_in, const int* in_sizes, int n_in,
                              void* d_out, int out_size, void* d_ws, size_t ws_size,
                              hipStream_t stream)
{
    const float* video      = (const float*)d_in[0];
    const float* conv_w     = (const float*)d_in[1];
    const float* conv_b     = (const float*)d_in[2];
    const float* wq_w       = (const float*)d_in[3];
    const float* wq_b       = (const float*)d_in[4];
    const float* wk_w       = (const float*)d_in[5];
    const float* wk_b       = (const float*)d_in[6];
    const float* wv_w       = (const float*)d_in[7];
    const float* wv_b       = (const float*)d_in[8];
    const float* lnq_g      = (const float*)d_in[9];
    const float* lnq_b      = (const float*)d_in[10];
    const float* lnk_g      = (const float*)d_in[11];
    const float* lnk_b      = (const float*)d_in[12];
    const float* lnv_g      = (const float*)d_in[13];
    const float* lnv_b      = (const float*)d_in[14];
    const float* in_proj_w  = (const float*)d_in[15];
    const float* in_proj_b  = (const float*)d_in[16];
    const float* out_proj_w = (const float*)d_in[17];
    const float* out_proj_b = (const float*)d_in[18];
    const float* dense_w    = (const float*)d_in[19];
    const float* dense_b    = (const float*)d_in[20];
    const float* bproj_w    = (const float*)d_in[21];
    const float* bproj_b    = (const float*)d_in[22];
    const float* group_q    = (const float*)d_in[23];
    const float* ent_table  = (const float*)d_in[24];
    float* out = (float*)d_out;

    // ---- workspace layout ----
    float* tokmean4 = (float*)d_ws;                      // 4*NTOK (pad to 16384)
    unsigned short* Pk  = (unsigned short*)(tokmean4 + 16384);   // pre-LN K (bf16)
    unsigned short* Pv  = Pk  + (size_t)MT * 256;        // pre-LN V (bf16)
    unsigned short* B1  = Pv  + (size_t)MT * 256;        // tokens
    unsigned short* B3v = B1  + (size_t)MT * 256;        // vp
    unsigned short* cwh = B3v + (size_t)MT * 256;        // conv weights hi (permuted)
    unsigned short* cwl = cwh + 256 * KCV;               // conv weights lo (permuted)
    unsigned short* wpool = cwl + 256 * KCV;             // bf16 weights pool
    float* sc = (float*)(wpool + 524288);                // scores [B*NH][NTOK]
    float* qp = sc + 16 * NTOK;
    int* boundary  = (int*)(qp + 256);
    int* seg_start = boundary + NTOK;
    int* Sp        = seg_start + (NTOK + 1);
    float* D1   = (float*)(Sp + 64);                     // 65536 fp32 (Wd@Wo)
    float* tvec = D1 + 65536;                            // 256
    float* bc   = tvec + 256;                            // 256

    // pool offsets: wk 0, wv 65536, in_proj 131072 (3E*E), Wc 327680
    const unsigned short* inpb = wpool + 131072;
    unsigned short* WcB        = wpool + 327680;

    dim3 blk(256);
    // 1) prep: split_cw + cast {wk,wv,in_proj} + query + D1=Wd@Wo + tvec
    prep_k<<<dim3(1826), blk, 0, stream>>>(conv_w, cwh, cwl,
                                           wk_w, wv_w, in_proj_w, wpool,
                                           group_q, wq_w, wq_b, lnq_g, lnq_b,
                                           in_proj_w, in_proj_b, qp,
                                           dense_w, out_proj_w, out_proj_b, dense_b,
                                           D1, tvec);
    // 2) conv (784) + prep2 piggyback (257): Wc = bproj_w@D1, bc
    conv_mfma_k<<<dim3(1041), blk, 0, stream>>>(video, cwh, cwl, conv_b, tokmean4, B1,
                                                bproj_w, D1, tvec, bproj_b, WcB, bc);
    // 3) K+V pre-LN GEMM (1568) + boundary piggyback (784)
    gemm_dual_k<<<dim3(2352), blk, 0, stream>>>(B1, B1, wpool, wk_b, wv_b, Pk, Pv,
                                                tokmean4, ent_table, boundary);
    // 4) LN-fused kp+vp projection (1568) + scan piggyback (1)
    gemm_ln_k<<<dim3(1569), blk, 0, stream>>>(Pk, Pv, inpb + 65536,
                                              in_proj_b + 256, in_proj_b + 512,
                                              lnk_g, lnk_b, lnv_g, lnv_b,
                                              B3v, qp, sc,
                                              boundary, seg_start, Sp);
    // 5) fused attention + final projection: out = softmaxPV @ Wc^T + bc, masked
    attn_proj_k<<<dim3(49, 4), blk, 0, stream>>>(sc, B3v, seg_start, Sp, WcB, bc, out);
}

// Round 12
// 296.410 us; speedup vs baseline: 1.1948x; 1.1948x over previous
//
#include <hip/hip_runtime.h>
#include <hip/hip_bf16.h>
#include <math.h>

#define NTOK 3136           // 16*14*14 tokens
#define MT 12544            // 4 * NTOK
#define KCV 2304            // 3*3*16*16
#define THRESH 1.5f
#define LN_EPS 1e-5f

typedef short short8 __attribute__((ext_vector_type(8)));
typedef float f32x4 __attribute__((ext_vector_type(4)));

// ---------- bf16 helpers ----------
__device__ __forceinline__ unsigned short f2bf(float f) {   // manual RTNE (cold paths)
    unsigned int u = __float_as_uint(f);
    u += 0x7fffu + ((u >> 16) & 1u);
    return (unsigned short)(u >> 16);
}
__device__ __forceinline__ float bf2f(unsigned short h) {
    return __uint_as_float(((unsigned int)h) << 16);
}
// HW packed cvt (v_cvt_pk_bf16_f32, RTNE): low16 = bf(x0), high16 = bf(x1)
__device__ __forceinline__ unsigned int cvt_pk_bf16(float x0, float x1) {
    union { __hip_bfloat162 h; unsigned int u; } cv;
    cv.h = __float22bfloat162_rn(make_float2(x0, x1));
    return cv.u;
}
__device__ __forceinline__ void async16(const void* g, void* l) {
    __builtin_amdgcn_global_load_lds((const __attribute__((address_space(1))) void*)g,
                                     (__attribute__((address_space(3))) void*)l, 16, 0, 0);
}

// ---------- wave helpers (wave = 64) ----------
__device__ __forceinline__ float wsum(float v) {
#pragma unroll
    for (int o = 32; o > 0; o >>= 1) v += __shfl_xor(v, o);
    return v;
}
__device__ __forceinline__ float wmax(float v) {
#pragma unroll
    for (int o = 32; o > 0; o >>= 1) v = fmaxf(v, __shfl_xor(v, o));
    return v;
}

// ---------- prep mega-kernel ----------
// blocks 0..287      : split_cw -> hi/lo bf16, permuted [kg][e][8]
// blocks 288..1567   : cast wk|wv|in_proj -> bf16 pool (offsets 0 / 65536 / 131072)
// block  1568        : query path -> qp[256]
// blocks 1569..1824  : D1 = dense_w @ out_proj_w (fp32, row per block)
// block  1825        : tvec = dense_w @ out_proj_b + dense_b + gq
__global__ __launch_bounds__(256) void prep_k(
    const float* __restrict__ cw, unsigned short* __restrict__ cwh,
    unsigned short* __restrict__ cwl,
    const float* __restrict__ s0, const float* __restrict__ s1, const float* __restrict__ s2,
    unsigned short* __restrict__ dst,
    const float* __restrict__ gq, const float* __restrict__ wq_w,
    const float* __restrict__ wq_b, const float* __restrict__ lnq_g,
    const float* __restrict__ lnq_b, const float* __restrict__ inW,
    const float* __restrict__ inB, float* __restrict__ qp,
    const float* __restrict__ Wd, const float* __restrict__ Wo,
    const float* __restrict__ bo, const float* __restrict__ bd,
    float* __restrict__ D1, float* __restrict__ tvec)
{
    const int blk = blockIdx.x;
    const int t = threadIdx.x;
    if (blk < 288) {
        int i = blk * 256 + t;                   // 288 kg * 256 e
        int e = i & 255, kg = i >> 8;
        const float4* sp = (const float4*)(cw + (size_t)e * KCV + kg * 8);
        float4 x0 = sp[0], x1 = sp[1];
        float av[8] = {x0.x, x0.y, x0.z, x0.w, x1.x, x1.y, x1.z, x1.w};
        short8 hh, ll;
#pragma unroll
        for (int j = 0; j < 8; ++j) {
            unsigned short h = f2bf(av[j]);
            hh[j] = (short)h;
            ll[j] = (short)f2bf(av[j] - bf2f(h));
        }
        size_t off = (size_t)kg * 2048 + e * 8;
        *(short8*)&cwh[off] = hh;
        *(short8*)&cwl[off] = ll;
    } else if (blk < 1568) {
        int i = (blk - 288) * 256 + t;           // 327680 total
        if (i >= 327680) return;
        float v;
        if      (i <  65536) v = s0[i];
        else if (i < 131072) v = s1[i - 65536];
        else                 v = s2[i - 131072];
        dst[i] = f2bf(v);
    } else if (blk == 1568) {
        // query path: qp[256], batch-invariant, fp32
        __shared__ float sh[256];
        __shared__ float red[256];
        float acc = wq_b[t];
        for (int j = 0; j < 256; j++) acc += gq[j] * wq_w[t * 256 + j];
        red[t] = acc; __syncthreads();
        for (int o = 128; o > 0; o >>= 1) { if (t < o) red[t] += red[t + o]; __syncthreads(); }
        float m = red[0] * (1.f / 256.f);
        __syncthreads();
        float d = acc - m;
        red[t] = d * d; __syncthreads();
        for (int o = 128; o > 0; o >>= 1) { if (t < o) red[t] += red[t + o]; __syncthreads(); }
        float inv = 1.f / sqrtf(red[0] * (1.f / 256.f) + LN_EPS);
        sh[t] = d * inv * lnq_g[t] + lnq_b[t];
        __syncthreads();
        float a2 = inB[t];
        for (int j = 0; j < 256; j++) a2 += sh[j] * inW[t * 256 + j];
        qp[t] = a2 * 0.125f;
    } else if (blk < 1825) {
        // D1 row i: D1[i][j] = sum_k Wd[i][k] * Wo[k][j]
        int i = blk - 1569;
        float acc = 0.f;
        for (int k = 0; k < 256; k++) acc += Wd[i * 256 + k] * Wo[k * 256 + t];
        D1[i * 256 + t] = acc;
    } else {
        // tvec[i] = sum_k Wd[i][k]*bo[k] + bd[i] + gq[i]
        float acc = bd[t] + gq[t];
        for (int k = 0; k < 256; k++) acc += Wd[t * 256 + k] * bo[k];
        tvec[t] = acc;
    }
}

// ---------- conv implicit GEMM (v5, proven 82.5us) + prep2 piggyback blocks ----------
// blocks 0..783 : conv. 64m x 64e, XCD swizzle, BK=64. A in registers (frag layout),
//   prefetch depth 1; B reg-staged + ds_write (barrier drains lgkm only).
// blocks 784..1039 : Wc row = bproj_w @ D1 -> bf16.  block 1040 : bc vector.
__global__ __launch_bounds__(256) void conv_mfma_k(
    const float* __restrict__ video, const unsigned short* __restrict__ cwh,
    const unsigned short* __restrict__ cwl, const float* __restrict__ cbias,
    float* __restrict__ tokmean4, unsigned short* __restrict__ outB,
    const float* __restrict__ Wb, const float* __restrict__ D1,
    const float* __restrict__ tvec, const float* __restrict__ bb,
    unsigned short* __restrict__ WcB, float* __restrict__ bc)
{
    __shared__ __align__(16) unsigned short Bh[8192], Bl[8192];  // 2 bufs x [kg8][e64][8]
    const int t    = threadIdx.x;
    if (blockIdx.x >= 784) {
        const int pblk = blockIdx.x - 784;
        if (pblk < 256) {
            float acc = 0.f;
            for (int k = 0; k < 256; k++) acc += Wb[pblk * 256 + k] * D1[k * 256 + t];
            WcB[pblk * 256 + t] = f2bf(acc);
        } else {
            float acc = bb[t];
            for (int k = 0; k < 256; k++) acc += Wb[t * 256 + k] * tvec[k];
            bc[t] = acc;
        }
        return;
    }
    const int lane = t & 63;
    const int w    = t >> 6;
    const int l15  = lane & 15, lq = lane >> 4;
    const int v_  = blockIdx.x;
    const int s_  = (v_ & 7) * 98 + (v_ >> 3);
    const int mb  = s_ >> 2, eb = s_ & 3;
    const int m0  = mb * 64, e0 = eb * 64;

    const int m = m0 + w * 16 + l15;
    const int b = m / NTOK, n = m % NTOK;
    const int d = n / 196, hw = n % 196;
    const int h = hw / 14, ww = hw % 14;
    const float* vb = video + (size_t)(b * 3) * (32 * 50176) + (h * 16) * 224 + ww * 16;
    const int dbase = 2 * d - 1;

    f32x4 acc[4] = {};
    float4 a0, a1, a2, a3, b0, b1, b2, b3;
    short8 rh0, rh1, rl0, rl1;

#define BLOAD(s)                                                                     \
    {                                                                                \
        const size_t g0 = (size_t)((s) * 8 + w) * 2048 + (e0 + lane) * 8;            \
        const size_t g1 = g0 + 4 * 2048;                                             \
        rh0 = *(const short8*)(cwh + g0);                                            \
        rh1 = *(const short8*)(cwh + g1);                                            \
        rl0 = *(const short8*)(cwl + g0);                                            \
        rl1 = *(const short8*)(cwl + g1);                                            \
    }
#define BSTORE(buf)                                                                  \
    {                                                                                \
        const int o = (buf) * 4096 + w * 512 + lane * 8;                             \
        *(short8*)&Bh[o]        = rh0;                                               \
        *(short8*)&Bh[o + 2048] = rh1;                                               \
        *(short8*)&Bl[o]        = rl0;                                               \
        *(short8*)&Bl[o + 2048] = rl1;                                               \
    }
#define LOAD_A32(k0v, x0, x1)                                                        \
    {                                                                                \
        const int k0  = (k0v) + lq * 8;                                              \
        const int c   = k0 / 768;                                                    \
        const int rem = k0 - c * 768;                                                \
        const int kd  = rem >> 8;                                                    \
        const int r2  = rem & 255;                                                   \
        const int id  = dbase + kd;                                                  \
        x0 = make_float4(0.f, 0.f, 0.f, 0.f); x1 = x0;                               \
        if (id >= 0) {                                                               \
            const float* p = vb + (size_t)c * (32 * 50176) + id * 50176 +            \
                             (r2 >> 4) * 224 + (r2 & 15);                            \
            x0 = *(const float4*)p;                                                  \
            x1 = *(const float4*)(p + 4);                                            \
        }                                                                            \
    }
#define CVT_AB(y0, y1, fah, fal)                                                     \
    short8 fah, fal;                                                                 \
    {                                                                                \
        float av[8] = {y0.x, y0.y, y0.z, y0.w, y1.x, y1.y, y1.z, y1.w};              \
        unsigned int ph[4], pl[4];                                                   \
        _Pragma("unroll")                                                            \
        for (int j = 0; j < 4; ++j) {                                                \
            float u0 = av[2 * j], u1 = av[2 * j + 1];                                \
            unsigned int hu = cvt_pk_bf16(u0, u1);                                   \
            float r0 = u0 - __uint_as_float(hu << 16);                               \
            float r1 = u1 - __uint_as_float(hu & 0xffff0000u);                       \
            ph[j] = hu;                                                              \
            pl[j] = cvt_pk_bf16(r0, r1);                                             \
        }                                                                            \
        int4 phv = make_int4(ph[0], ph[1], ph[2], ph[3]);                            \
        int4 plv = make_int4(pl[0], pl[1], pl[2], pl[3]);                            \
        fah = *(short8*)&phv;                                                        \
        fal = *(short8*)&plv;                                                        \
    }

    BLOAD(0);
    LOAD_A32(0, a0, a1);
    LOAD_A32(32, a2, a3);
    BSTORE(0);
    __syncthreads();

    for (int s = 0; s < 36; ++s) {
        const int cbuf = s & 1;
        if (s + 1 < 36) {
            BLOAD(s + 1);
            LOAD_A32((s + 1) * 64,      b0, b1);
            LOAD_A32((s + 1) * 64 + 32, b2, b3);
        }
        {
            CVT_AB(a0, a1, fah, fal);
            const int rb = cbuf * 4096 + lq * 512 + l15 * 8;
#pragma unroll
            for (int ct = 0; ct < 4; ++ct) {
                short8 fbh = *(const short8*)&Bh[rb + ct * 128];
                short8 fbl = *(const short8*)&Bl[rb + ct * 128];
                acc[ct] = __builtin_amdgcn_mfma_f32_16x16x32_bf16(fah, fbh, acc[ct], 0, 0, 0);
                acc[ct] = __builtin_amdgcn_mfma_f32_16x16x32_bf16(fah, fbl, acc[ct], 0, 0, 0);
                acc[ct] = __builtin_amdgcn_mfma_f32_16x16x32_bf16(fal, fbh, acc[ct], 0, 0, 0);
            }
        }
        {
            CVT_AB(a2, a3, fah, fal);
            const int rb = cbuf * 4096 + (4 + lq) * 512 + l15 * 8;
#pragma unroll
            for (int ct = 0; ct < 4; ++ct) {
                short8 fbh = *(const short8*)&Bh[rb + ct * 128];
                short8 fbl = *(const short8*)&Bl[rb + ct * 128];
                acc[ct] = __builtin_amdgcn_mfma_f32_16x16x32_bf16(fah, fbh, acc[ct], 0, 0, 0);
                acc[ct] = __builtin_amdgcn_mfma_f32_16x16x32_bf16(fah, fbl, acc[ct], 0, 0, 0);
                acc[ct] = __builtin_amdgcn_mfma_f32_16x16x32_bf16(fal, fbh, acc[ct], 0, 0, 0);
            }
        }
        if (s + 1 < 36) BSTORE(cbuf ^ 1);
        __syncthreads();
        a0 = b0; a1 = b1; a2 = b2; a3 = b3;
    }
#undef BLOAD
#undef BSTORE
#undef LOAD_A32
#undef CVT_AB

    // C/D: col(e) = lane&15, row(m) = (lane>>4)*4 + reg  [m89]
    const int rbase = m0 + w * 16 + lq * 4;
    float rsum[4] = {0.f, 0.f, 0.f, 0.f};
#pragma unroll
    for (int ct = 0; ct < 4; ++ct) {
        int e = e0 + ct * 16 + l15;
        float bias = cbias[e];
#pragma unroll
        for (int r = 0; r < 4; ++r) {
            float vv = fmaxf(acc[ct][r] + bias, 0.f);
            outB[(size_t)(rbase + r) * 256 + e] = f2bf(vv);
            rsum[r] += vv;
        }
    }
    if (m0 < NTOK) {
#pragma unroll
        for (int r = 0; r < 4; ++r) {
            float sv = rsum[r];
            sv += __shfl_xor(sv, 1); sv += __shfl_xor(sv, 2);
            sv += __shfl_xor(sv, 4); sv += __shfl_xor(sv, 8);
            if (l15 == 0) tokmean4[(size_t)eb * NTOK + rbase + r] = sv;
        }
    }
}

// ---------- dual-output GEMM (blocks 0..783) + boundary piggyback (784..1567) ----------
// Each block computes BOTH Pk and Pv 64x64 tiles for its (mb, el): A (tokens) staged
// ONCE per k-phase (was staged twice across the wk/wv halves), two W tiles streamed.
// 64 MFMA/wave per block (2x the old dual), half the blocks -> same MFMA total,
// half the A traffic + barrier overhead. Numerics identical.
__global__ __launch_bounds__(256) void gemm_dual_k(
    const unsigned short* __restrict__ A0, const unsigned short* __restrict__ W,
    const float* __restrict__ biask, const float* __restrict__ biasv,
    unsigned short* __restrict__ outPk, unsigned short* __restrict__ outPv,
    const float* __restrict__ tokmean4, const float* __restrict__ ent_table,
    int* __restrict__ boundary)
{
    __shared__ __align__(16) unsigned short As[8192], Bk[8192], Bv[8192];  // 48 KB
    const int t = threadIdx.x, lane = t & 63, w = t >> 6;
    if (blockIdx.x >= 784) {
        // boundary: one wave per token (needs tokmean4 from conv launch)
        int n = (blockIdx.x - 784) * 4 + w;
        float s0 = tokmean4[n];
        float s1 = tokmean4[NTOK + n];
        float s2 = tokmean4[2 * NTOK + n];
        float s3 = tokmean4[3 * NTOK + n];
        float mean = ((s0 + s1) + (s2 + s3)) * (1.f / 256.f);   // deterministic order
        float bf = rintf(mean * 255.f);
        bf = fminf(fmaxf(bf, 0.f), 255.f);
        int byte = (int)bf;
        const float4 lg = reinterpret_cast<const float4*>(ent_table + byte * 256)[lane];
        float mx = wmax(fmaxf(fmaxf(lg.x, lg.y), fmaxf(lg.z, lg.w)));
        float e0 = expf(lg.x - mx), e1 = expf(lg.y - mx);
        float e2 = expf(lg.z - mx), e3 = expf(lg.w - mx);
        float z = wsum(e0 + e1 + e2 + e3);
        float iz = 1.f / z;
        float p0 = e0 * iz, p1 = e1 * iz, p2 = e2 * iz, p3 = e3 * iz;
        float ep = -(p0 * log2f(p0 + 1e-9f) + p1 * log2f(p1 + 1e-9f) +
                     p2 * log2f(p2 + 1e-9f) + p3 * log2f(p3 + 1e-9f));
        ep = wsum(ep);
        if (lane == 0) boundary[n] = (ep > THRESH) ? 1 : 0;
        return;
    }
    const int v_ = blockIdx.x;
    const int s_ = (v_ & 7) * 98 + (v_ >> 3);          // 784 = 8*98
    const int mb = s_ >> 2, el = s_ & 3;
    const int m0 = mb * 64, e0 = el * 64;
    const int l15 = lane & 15, lq = lane >> 4;
    const unsigned short* ga  = A0 + (size_t)(m0 + lane) * 256;
    const unsigned short* gbk = W + (size_t)(e0 + lane) * 256;          // wk rows
    const unsigned short* gbv = W + (size_t)(256 + e0 + lane) * 256;    // wv rows
    f32x4 acck[4] = {}, accv[4] = {};
#pragma unroll
    for (int ph = 0; ph < 2; ++ph) {
        const int ko = ph * 16;                // kg offset of this phase
        if (ph == 1) __syncthreads();          // phase-0 reads done before overwrite
#pragma unroll
        for (int kg = w; kg < 16; kg += 4) {
            async16(ga  + (ko + kg) * 8, &As[kg * 512]);
            async16(gbk + (ko + kg) * 8, &Bk[kg * 512]);
            async16(gbv + (ko + kg) * 8, &Bv[kg * 512]);
        }
        __syncthreads();
#pragma unroll
        for (int s = 0; s < 4; ++s) {
            int kg = s * 4 + lq;
            short8 a = *(const short8*)&As[kg * 512 + (w * 16 + l15) * 8];
#pragma unroll
            for (int ct = 0; ct < 4; ++ct) {
                short8 bk = *(const short8*)&Bk[kg * 512 + (ct * 16 + l15) * 8];
                short8 bv = *(const short8*)&Bv[kg * 512 + (ct * 16 + l15) * 8];
                acck[ct] = __builtin_amdgcn_mfma_f32_16x16x32_bf16(a, bk, acck[ct], 0, 0, 0);
                accv[ct] = __builtin_amdgcn_mfma_f32_16x16x32_bf16(a, bv, accv[ct], 0, 0, 0);
            }
        }
    }
    int rbase = m0 + w * 16 + lq * 4;
#pragma unroll
    for (int ct = 0; ct < 4; ++ct) {
        int e = e0 + ct * 16 + l15;
        float bvk = biask[e], bvv = biasv[e];
#pragma unroll
        for (int r = 0; r < 4; ++r) {
            size_t off = (size_t)(rbase + r) * 256 + e;
            outPk[off] = f2bf(acck[ct][r] + bvk);
            outPv[off] = f2bf(accv[ct][r] + bvv);
        }
    }
}

// ---------- LN-fused dual GEMM (blocks 0..1567) + scan piggyback (block 1568) ----------
// B staged in TWO phases (16KB). half0 (kp): scores epilogue (dot qp), kp never
// stored. half1 (vp): store bf16.
__global__ __launch_bounds__(256, 2) void gemm_ln_k(
    const unsigned short* __restrict__ A0, const unsigned short* __restrict__ A1,
    const unsigned short* __restrict__ W,
    const float* __restrict__ bias0, const float* __restrict__ bias1,
    const float* __restrict__ g0, const float* __restrict__ b0,
    const float* __restrict__ g1, const float* __restrict__ b1,
    unsigned short* __restrict__ outVp, const float* __restrict__ qp,
    float* __restrict__ sc,
    const int* __restrict__ boundary, int* __restrict__ seg_start, int* __restrict__ Sptr)
{
    __shared__ __align__(16) unsigned short As[16384], Bs[8192];   // 32 KB + 16 KB
    __shared__ float pst[2][4][64];
    __shared__ float rmean[64], rinv[64];
    __shared__ int sums[256];
    const int t = threadIdx.x, lane = t & 63, w = t >> 6;
    if (blockIdx.x >= 1568) {
        // single-block scan: boundary -> seg_start[], S
        const int CH = 13;
        int base = t * CH;
        int s = 0;
        for (int i = 0; i < CH; i++) { int n = base + i; if (n < NTOK) s += boundary[n]; }
        sums[t] = s; __syncthreads();
        for (int o = 1; o < 256; o <<= 1) {
            int v = sums[t];
            int u = (t >= o) ? sums[t - o] : 0;
            __syncthreads();
            sums[t] = v + u;
            __syncthreads();
        }
        int run = (t == 0) ? 0 : sums[t - 1];
        if (t == 0) seg_start[0] = 0;
        for (int i = 0; i < CH; i++) {
            int n = base + i;
            if (n >= NTOK) break;
            int v = boundary[n];
            if (n == NTOK - 1) { Sptr[0] = run + 1; seg_start[run + 1] = NTOK; }
            if (v && (n + 1 < NTOK)) seg_start[run + 1] = n + 1;
            run += v;
        }
        return;
    }
    const int v_ = blockIdx.x;
    const int s_ = (v_ & 7) * 196 + (v_ >> 3);         // 1568 = 8*196
    const int mb = s_ >> 3, ebg = s_ & 7;
    const int half = ebg >> 2;
    const unsigned short* A = half ? A1 : A0;
    const float* bias = half ? bias1 : bias0;
    const float* lng  = half ? g1 : g0;
    const float* lnb  = half ? b1 : b0;
    const int m0 = mb * 64, eg0 = ebg * 64, el0 = (ebg & 3) * 64;
    const int l15 = lane & 15, lq = lane >> 4;
    const unsigned short* ga = A + (size_t)(m0 + lane) * 256;
    const unsigned short* gb = W + (size_t)(eg0 + lane) * 256;
    // stage FULL A (32 kg) + B phase 1 (kg 0..15)
#pragma unroll
    for (int kg = w; kg < 32; kg += 4) async16(ga + kg * 8, &As[kg * 512]);
#pragma unroll
    for (int kg = w; kg < 16; kg += 4) async16(gb + kg * 8, &Bs[kg * 512]);
    __syncthreads();
    // row stats: lane l owns row l; wave w sums its kg quarter [w*8, w*8+8)
    {
        float sum = 0.f, sq = 0.f;
#pragma unroll
        for (int k8 = 0; k8 < 8; ++k8) {
            short8 x = *(const short8*)&As[(w * 8 + k8) * 512 + lane * 8];
#pragma unroll
            for (int j = 0; j < 8; ++j) {
                float xv = bf2f((unsigned short)x[j]);
                sum += xv; sq += xv * xv;
            }
        }
        pst[0][w][lane] = sum; pst[1][w][lane] = sq;
    }
    __syncthreads();
    if (w == 0) {
        float s4 = (pst[0][0][lane] + pst[0][1][lane]) + (pst[0][2][lane] + pst[0][3][lane]);
        float q4 = (pst[1][0][lane] + pst[1][1][lane]) + (pst[1][2][lane] + pst[1][3][lane]);
        float mean = s4 * (1.f / 256.f);
        float var  = q4 * (1.f / 256.f) - mean * mean;
        rmean[lane] = mean;
        rinv[lane]  = 1.f / sqrtf(var + LN_EPS);
    }
    __syncthreads();
    const float myMean = rmean[w * 16 + l15];
    const float myInv  = rinv [w * 16 + l15];

    f32x4 acc[4] = {};
#pragma unroll
    for (int ph = 0; ph < 2; ++ph) {
        if (ph == 1) {
            __syncthreads();                       // phase-1 B reads done
#pragma unroll
            for (int kg = w; kg < 16; kg += 4) async16(gb + (16 + kg) * 8, &Bs[kg * 512]);
            __syncthreads();
        }
#pragma unroll
        for (int s = 0; s < 4; ++s) {
            int kg = ph * 16 + s * 4 + lq;         // global kg 0..31
            short8 araw = *(const short8*)&As[kg * 512 + (w * 16 + l15) * 8];
            float4 gA = *(const float4*)&lng[kg * 8];
            float4 gB = *(const float4*)&lng[kg * 8 + 4];
            float4 bA = *(const float4*)&lnb[kg * 8];
            float4 bB = *(const float4*)&lnb[kg * 8 + 4];
            float y[8];
            y[0] = (bf2f((unsigned short)araw[0]) - myMean) * myInv * gA.x + bA.x;
            y[1] = (bf2f((unsigned short)araw[1]) - myMean) * myInv * gA.y + bA.y;
            y[2] = (bf2f((unsigned short)araw[2]) - myMean) * myInv * gA.z + bA.z;
            y[3] = (bf2f((unsigned short)araw[3]) - myMean) * myInv * gA.w + bA.w;
            y[4] = (bf2f((unsigned short)araw[4]) - myMean) * myInv * gB.x + bB.x;
            y[5] = (bf2f((unsigned short)araw[5]) - myMean) * myInv * gB.y + bB.y;
            y[6] = (bf2f((unsigned short)araw[6]) - myMean) * myInv * gB.z + bB.z;
            y[7] = (bf2f((unsigned short)araw[7]) - myMean) * myInv * gB.w + bB.w;
            int4 pk = make_int4(cvt_pk_bf16(y[0], y[1]), cvt_pk_bf16(y[2], y[3]),
                                cvt_pk_bf16(y[4], y[5]), cvt_pk_bf16(y[6], y[7]));
            short8 a = *(short8*)&pk;
            const int bkg = s * 4 + lq;            // B buffer index (0..15)
#pragma unroll
            for (int ct = 0; ct < 4; ++ct) {
                short8 bb = *(const short8*)&Bs[bkg * 512 + (ct * 16 + l15) * 8];
                acc[ct] = __builtin_amdgcn_mfma_f32_16x16x32_bf16(a, bb, acc[ct], 0, 0, 0);
            }
        }
    }
    int rbase = m0 + w * 16 + lq * 4;
    if (half == 0) {
        float sp[4] = {0.f, 0.f, 0.f, 0.f};
#pragma unroll
        for (int ct = 0; ct < 4; ++ct) {
            int e = el0 + ct * 16 + l15;
            float bv = bias[e];
            float qv = qp[e];
#pragma unroll
            for (int r = 0; r < 4; ++r) sp[r] += (acc[ct][r] + bv) * qv;
        }
#pragma unroll
        for (int r = 0; r < 4; ++r) {
            sp[r] += __shfl_xor(sp[r], 1); sp[r] += __shfl_xor(sp[r], 2);
            sp[r] += __shfl_xor(sp[r], 4); sp[r] += __shfl_xor(sp[r], 8);
        }
        if (l15 == 0) {
#pragma unroll
            for (int r = 0; r < 4; ++r) {
                int mm = rbase + r;
                int bb = mm / NTOK, nn = mm % NTOK;
                sc[(bb * 4 + ebg) * NTOK + nn] = sp[r];
            }
        }
    } else {
#pragma unroll
        for (int ct = 0; ct < 4; ++ct) {
            int e = el0 + ct * 16 + l15;
            float bv = bias[e];
#pragma unroll
            for (int r = 0; r < 4; ++r) {
                float vv = acc[ct][r] + bv;
                outVp[(size_t)(rbase + r) * 256 + e] = f2bf(vv);
            }
        }
    }
}

// ---------- bf16 MFMA GEMM, K=256, 2-phase staging, XCD swizzle (784 blocks) ----------
__global__ __launch_bounds__(256) void gemm_single_k(
    const unsigned short* __restrict__ A, const unsigned short* __restrict__ W,
    const float* __restrict__ bias, const float* __restrict__ addvec,
    const int* __restrict__ Sptr, float* __restrict__ outF, unsigned short* __restrict__ outB)
{
    __shared__ __align__(16) unsigned short As[8192], Bs[8192];   // 16 KB + 16 KB
    const int t = threadIdx.x, lane = t & 63, w = t >> 6;
    const int v_ = blockIdx.x;
    const int s_ = (v_ & 7) * 98 + (v_ >> 3);          // 784 = 8*98
    const int m0 = (s_ >> 2) * 64, e0 = (s_ & 3) * 64;
    const int l15 = lane & 15, lq = lane >> 4;
    const unsigned short* ga = A + (size_t)(m0 + lane) * 256;
    const unsigned short* gb = W + (size_t)(e0 + lane) * 256;
#pragma unroll
    for (int kg = w; kg < 16; kg += 4) {
        async16(ga + kg * 8, &As[kg * 512]);
        async16(gb + kg * 8, &Bs[kg * 512]);
    }
    f32x4 acc[4] = {};
    __syncthreads();
#pragma unroll
    for (int s = 0; s < 4; ++s) {
        int kg = s * 4 + lq;
        short8 a = *(const short8*)&As[kg * 512 + (w * 16 + l15) * 8];
#pragma unroll
        for (int ct = 0; ct < 4; ++ct) {
            short8 bb = *(const short8*)&Bs[kg * 512 + (ct * 16 + l15) * 8];
            acc[ct] = __builtin_amdgcn_mfma_f32_16x16x32_bf16(a, bb, acc[ct], 0, 0, 0);
        }
    }
    __syncthreads();
#pragma unroll
    for (int kg = w; kg < 16; kg += 4) {
        async16(ga + (16 + kg) * 8, &As[kg * 512]);
        async16(gb + (16 + kg) * 8, &Bs[kg * 512]);
    }
    __syncthreads();
#pragma unroll
    for (int s = 0; s < 4; ++s) {
        int kg = s * 4 + lq;
        short8 a = *(const short8*)&As[kg * 512 + (w * 16 + l15) * 8];
#pragma unroll
        for (int ct = 0; ct < 4; ++ct) {
            short8 bb = *(const short8*)&Bs[kg * 512 + (ct * 16 + l15) * 8];
            acc[ct] = __builtin_amdgcn_mfma_f32_16x16x32_bf16(a, bb, acc[ct], 0, 0, 0);
        }
    }
    int S = Sptr ? *Sptr : 0x7fffffff;
    int rbase = m0 + w * 16 + lq * 4;
#pragma unroll
    for (int ct = 0; ct < 4; ++ct) {
        int e = e0 + ct * 16 + l15;
        float bv = bias[e] + (addvec ? addvec[e] : 0.f);
#pragma unroll
        for (int r = 0; r < 4; ++r) {
            int mm = rbase + r;
            float vv = acc[ct][r] + bv;
            if ((mm % NTOK) >= S) vv = 0.f;
            size_t off = (size_t)mm * 256 + e;
            if (outF) outF[off] = vv;
            if (outB) outB[off] = f2bf(vv);
        }
    }
}

// ---------- segment softmax-attention; grid-stride over segments; wave = head ----------
// s >= S segments: no write (final GEMM zeroes masked rows; stale B1 rows are finite).
__global__ __launch_bounds__(256) void attn_bf_k(const float* __restrict__ sc,
    const unsigned short* __restrict__ vp, const int* __restrict__ seg_start,
    const int* __restrict__ Sptr, unsigned short* __restrict__ attn)
{
    int b    = blockIdx.y;
    int h    = threadIdx.x >> 6;
    int lane = threadIdx.x & 63;
    int S = *Sptr;
    const unsigned short* vpb0 = vp + (size_t)b * NTOK * 256 + h * 64 + lane;
    for (int s = blockIdx.x; s < S; s += gridDim.x) {
        int st = seg_start[s], en = seg_start[s + 1];
        const float* scr = sc + (b * 4 + h) * NTOK;
        float m = -1e30f;
        for (int n = st; n < en; n++) m = fmaxf(m, scr[n]);
        float den = 0.f, acc = 0.f;
        for (int n = st; n < en; n++) {
            float wgt = expf(scr[n] - m);
            den += wgt;
            acc += wgt * bf2f(vpb0[(size_t)n * 256]);
        }
        attn[((size_t)b * NTOK + s) * 256 + h * 64 + lane] = f2bf(acc / den);
    }
}

extern "C" void kernel_launch(void* const* d_in, const int* in_sizes, int n_in,
                              void* d_out, int out_size, void* d_ws, size_t ws_size,
                              hipStream_t stream)
{
    const float* video      = (const float*)d_in[0];
    const float* conv_w     = (const float*)d_in[1];
    const float* conv_b     = (const float*)d_in[2];
    const float* wq_w       = (const float*)d_in[3];
    const float* wq_b       = (const float*)d_in[4];
    const float* wk_w       = (const float*)d_in[5];
    const float* wk_b       = (const float*)d_in[6];
    const float* wv_w       = (const float*)d_in[7];
    const float* wv_b       = (const float*)d_in[8];
    const float* lnq_g      = (const float*)d_in[9];
    const float* lnq_b      = (const float*)d_in[10];
    const float* lnk_g      = (const float*)d_in[11];
    const float* lnk_b      = (const float*)d_in[12];
    const float* lnv_g      = (const float*)d_in[13];
    const float* lnv_b      = (const float*)d_in[14];
    const float* in_proj_w  = (const float*)d_in[15];
    const float* in_proj_b  = (const float*)d_in[16];
    const float* out_proj_w = (const float*)d_in[17];
    const float* out_proj_b = (const float*)d_in[18];
    const float* dense_w    = (const float*)d_in[19];
    const float* dense_b    = (const float*)d_in[20];
    const float* bproj_w    = (const float*)d_in[21];
    const float* bproj_b    = (const float*)d_in[22];
    const float* group_q    = (const float*)d_in[23];
    const float* ent_table  = (const float*)d_in[24];
    float* out = (float*)d_out;

    // ---- workspace layout ----
    float* tokmean4 = (float*)d_ws;                      // 4*NTOK (pad to 16384)
    unsigned short* Pk  = (unsigned short*)(tokmean4 + 16384);   // pre-LN K (bf16)
    unsigned short* Pv  = Pk  + (size_t)MT * 256;        // pre-LN V (bf16)
    unsigned short* B1  = Pv  + (size_t)MT * 256;        // tokens / attn-out
    unsigned short* B3v = B1  + (size_t)MT * 256;        // vp
    unsigned short* cwh = B3v + (size_t)MT * 256;        // conv weights hi (permuted)
    unsigned short* cwl = cwh + 256 * KCV;               // conv weights lo (permuted)
    unsigned short* wpool = cwl + 256 * KCV;             // bf16 weights pool
    float* sc = (float*)(wpool + 524288);                // scores [B*NH][NTOK]
    float* qp = sc + 16 * NTOK;
    int* boundary  = (int*)(qp + 256);
    int* seg_start = boundary + NTOK;
    int* Sp        = seg_start + (NTOK + 1);
    float* D1   = (float*)(Sp + 64);                     // 65536 fp32 (Wd@Wo)
    float* tvec = D1 + 65536;                            // 256
    float* bc   = tvec + 256;                            // 256

    // pool offsets: wk 0, wv 65536, in_proj 131072 (3E*E), Wc 327680
    const unsigned short* inpb = wpool + 131072;
    unsigned short* WcB        = wpool + 327680;

    dim3 blk(256);
    // 1) prep: split_cw + cast {wk,wv,in_proj} + query + D1=Wd@Wo + tvec
    prep_k<<<dim3(1826), blk, 0, stream>>>(conv_w, cwh, cwl,
                                           wk_w, wv_w, in_proj_w, wpool,
                                           group_q, wq_w, wq_b, lnq_g, lnq_b,
                                           in_proj_w, in_proj_b, qp,
                                           dense_w, out_proj_w, out_proj_b, dense_b,
                                           D1, tvec);
    // 2) conv (784) + prep2 piggyback (257): Wc = bproj_w@D1, bc
    conv_mfma_k<<<dim3(1041), blk, 0, stream>>>(video, cwh, cwl, conv_b, tokmean4, B1,
                                                bproj_w, D1, tvec, bproj_b, WcB, bc);
    // 3) K+V pre-LN dual-output GEMM (784) + boundary piggyback (784)
    gemm_dual_k<<<dim3(1568), blk, 0, stream>>>(B1, wpool, wk_b, wv_b, Pk, Pv,
                                                tokmean4, ent_table, boundary);
    // 4) LN-fused kp+vp projection (1568) + scan piggyback (1)
    gemm_ln_k<<<dim3(1569), blk, 0, stream>>>(Pk, Pv, inpb + 65536,
                                              in_proj_b + 256, in_proj_b + 512,
                                              lnk_g, lnk_b, lnv_g, lnv_b,
                                              B3v, qp, sc,
                                              boundary, seg_start, Sp);
    // 5) segment attention: grid-stride over segments, 4 waves = 4 heads
    attn_bf_k<<<dim3(784, 4), blk, 0, stream>>>(sc, B3v, seg_start, Sp, B1);
    // 6) single fused tail: out = attn @ (Wb Wd Wo)^T + bc, masked
    gemm_single_k<<<dim3(784), blk, 0, stream>>>(B1, WcB, bc,
                                                 nullptr, Sp, out, nullptr);
}